// Round 1
// 99.404 us; speedup vs baseline: 1.0193x; 1.0193x over previous
//
#include <hip/hip_runtime.h>

#define NN 50000
#define BB 32
#define KK 32
#define TN 64   // nodes per block in prep kernel
#define GN 8    // nodes per block in gather kernel (NN % GN == 0)

// sqrt(log2(e)): folded into W/bias in fp16 so exp(-x) == exp2(-acc) with no
// per-iteration multiply by log2(e).
#define SQRT_LOG2E 1.2011244339448344f

typedef __attribute__((ext_vector_type(2))) _Float16 half2_t;
typedef __attribute__((ext_vector_type(4))) _Float16 half4_t;
typedef __attribute__((ext_vector_type(8))) _Float16 half8_t;

__device__ __forceinline__ half4_t g_dup0(half8_t v) {
    return __builtin_shufflevector(v, v, 0, 1, 0, 1);
}
__device__ __forceinline__ half4_t g_dup1(half8_t v) {
    return __builtin_shufflevector(v, v, 2, 3, 2, 3);
}
__device__ __forceinline__ half4_t g_dup2(half8_t v) {
    return __builtin_shufflevector(v, v, 4, 5, 4, 5);
}

// 8-lane reduce-to-lane-0 via DPP row_shl adds (pure VALU, no DS pipe).
// row_shl:N -> lane i reads lane i+N (within the 16-lane row); subgroups are
// 8-lane aligned so lanes 0 and 8 of each row end up with their group's sum.
__device__ __forceinline__ float red8(float v) {
    int t;
    t = __builtin_amdgcn_update_dpp(0, __builtin_bit_cast(int, v),
                                    0x104 /*row_shl:4*/, 0xF, 0xF, true);
    v += __builtin_bit_cast(float, t);
    t = __builtin_amdgcn_update_dpp(0, __builtin_bit_cast(int, v),
                                    0x102 /*row_shl:2*/, 0xF, 0xF, true);
    v += __builtin_bit_cast(float, t);
    t = __builtin_amdgcn_update_dpp(0, __builtin_bit_cast(int, v),
                                    0x101 /*row_shl:1*/, 0xF, 0xF, true);
    v += __builtin_bit_cast(float, t);
    return v;
}

// Prep: store what gather needs to RECOMPUTE f on the fly, in fp16:
//   xT[n][b2] = half2(x[2b2,n], x[2b2+1,n])         (64 B/node row)
//   gh[n]     = half8: dwords = (g0,g0),(g1,g1),(g2,g2),(0,0)  (16 B/node)
// g[j] = SQRT_LOG2E * (sum_e emb[n,e]*W[j,e] + bias[j]); the sqrt(log2e)
// prescale (also applied to ws in gather) makes acc = log2(e)*sum(d^2), so
// the gather can use v_exp_f32 (exp2) directly.
// Random-gather working set: 3.2 + 0.8 = 4 MB (L2-resident).
__global__ __launch_bounds__(256) void prep_kernel(
    const float* __restrict__ x,      // (B,N)
    const float* __restrict__ emb,    // (N,6)
    const float* __restrict__ W,      // (3,6)
    const float* __restrict__ bias,   // (3,)
    half2_t* __restrict__ xT,         // (N,16)
    half8_t* __restrict__ gh)         // (N)
{
    __shared__ float xs[BB][TN + 1];  // +1 pad: transpose read conflict-free

    const int n0 = blockIdx.x * TN;
    const int t  = threadIdx.x;

#pragma unroll
    for (int j = 0; j < 8; ++j) {
        int idx = j * 256 + t;        // 0..2047
        int r = idx >> 6, c = idx & 63;
        int n = n0 + c;
        xs[r][c] = (n < NN) ? x[r * NN + n] : 0.f;
    }
    __syncthreads();

#pragma unroll
    for (int it = 0; it < 4; ++it) {
        int slot = it * 256 + t;      // 0..1023
        int nl = slot >> 4, b2 = slot & 15;
        int n = n0 + nl;
        if (n < NN) {
            half2_t p;
            p.x = (_Float16)xs[2 * b2][nl];
            p.y = (_Float16)xs[2 * b2 + 1][nl];
            xT[n * 16 + b2] = p;                // 16 lanes -> 64B contiguous
            if (b2 == 0) {
                float e[6];
#pragma unroll
                for (int q = 0; q < 6; ++q) e[q] = emb[n * 6 + q];
                half8_t gv;
#pragma unroll
                for (int j = 0; j < 3; ++j) {
                    float s = bias[j];
#pragma unroll
                    for (int q = 0; q < 6; ++q) s += e[q] * W[j * 6 + q];
                    s *= SQRT_LOG2E;
                    gv[2 * j] = (_Float16)s;
                    gv[2 * j + 1] = (_Float16)s;
                }
                gv[6] = (_Float16)0.f; gv[7] = (_Float16)0.f;
                gh[n] = gv;
            }
        }
    }
}

// Gather: block = 8 nodes (grid 6250). 32 subgroups of 8 lanes; subgroup
// sg owns node (sg>>2) and k-range (sg&3)*8..+7, lane l holds b = 4l..4l+3
// as one half4 (2 pk ops per vector op). fn lives in registers; 8 fully-
// unrolled k-iterations give 16 independent L2 gathers to pipeline.
// Inner-loop cross-lane work is DPP-only (no DS ops); exp is raw v_exp_f32
// (log2e pre-folded into fp16 constants); gathered addresses are u32 byte
// offsets off a scalar base (workspace < 4 MB).
__global__ __launch_bounds__(256) void gather_kernel(
    const half4_t* __restrict__ xT4,  // (N,8) viewed as half4
    const half8_t* __restrict__ gh,   // (N)
    const float* __restrict__ W,      // (3,6)
    const int* __restrict__ nbr,      // (N,K)
    float* __restrict__ out)          // (N,K)
{
    __shared__ int nbr_sh[GN * KK];   // 8 nodes x 32 k

    const int t  = threadIdx.x;
    const int n0 = blockIdx.x * GN;

    nbr_sh[t] = nbr[n0 * KK + t];
    __syncthreads();

    // ws[j] = SQRT_LOG2E * sum_e W[j,e], duplicated across half4.
    half4_t ws4[3];
#pragma unroll
    for (int j = 0; j < 3; ++j) {
        float s = 0.f;
#pragma unroll
        for (int q = 0; q < 6; ++q) s += W[j * 6 + q];
        _Float16 h = (_Float16)(s * SQRT_LOG2E);
        ws4[j].x = h; ws4[j].y = h; ws4[j].z = h; ws4[j].w = h;
    }
    half4_t lk;
    lk.x = (_Float16)0.2f; lk.y = (_Float16)0.2f;
    lk.z = (_Float16)0.2f; lk.w = (_Float16)0.2f;

    const int l  = t & 7;             // lane in subgroup
    const int sg = t >> 3;            // 0..31
    const int nl = sg >> 2;           // node local 0..7
    const int kg = (sg & 3) * 8;      // k base
    const int n  = n0 + nl;

    const char* xb = (const char*)xT4;
    const char* gb = (const char*)gh;
    const unsigned xoff = (unsigned)(l * 8);

    // Center features for this lane's 4 b's (registers, once per subgroup).
    half4_t xn4 = *(const half4_t*)(xb + (unsigned)n * 64u + xoff);
    half8_t gn8 = *(const half8_t*)(gb + (unsigned)n * 16u);
    half4_t fn[3];
    {
        half4_t u0 = xn4 * ws4[0] + g_dup0(gn8);
        fn[0] = __builtin_elementwise_max(u0, u0 * lk);
        half4_t u1 = xn4 * ws4[1] + g_dup1(gn8);
        fn[1] = __builtin_elementwise_max(u1, u1 * lk);
        half4_t u2 = xn4 * ws4[2] + g_dup2(gn8);
        fn[2] = __builtin_elementwise_max(u2, u2 * lk);
    }

    const int mbase   = nl * KK + kg; // nbr_sh base for this subgroup
    const int outbase = n * KK + kg;

    int mlist[8];
#pragma unroll
    for (int i = 0; i < 8; ++i) mlist[i] = nbr_sh[mbase + i];

#pragma unroll
    for (int i = 0; i < 8; ++i) {
        int m  = mlist[i];
        int mc = m > 0 ? m : 0;
        half4_t xm4 = *(const half4_t*)(xb + (unsigned)mc * 64u + xoff);
        half8_t gm8 = *(const half8_t*)(gb + (unsigned)mc * 16u);

        half4_t u, d, acc;
        u = xm4 * ws4[0] + g_dup0(gm8);
        u = __builtin_elementwise_max(u, u * lk);
        d = fn[0] - u; acc = d * d;
        u = xm4 * ws4[1] + g_dup1(gm8);
        u = __builtin_elementwise_max(u, u * lk);
        d = fn[1] - u; acc = d * d + acc;
        u = xm4 * ws4[2] + g_dup2(gm8);
        u = __builtin_elementwise_max(u, u * lk);
        d = fn[2] - u; acc = d * d + acc;

        float v = (__builtin_amdgcn_exp2f(-(float)acc.x) +
                   __builtin_amdgcn_exp2f(-(float)acc.y)) +
                  (__builtin_amdgcn_exp2f(-(float)acc.z) +
                   __builtin_amdgcn_exp2f(-(float)acc.w));
        v = red8(v);
        if (l == 0) out[outbase + i] = (m < 0) ? 0.f : v * (1.0f / 32.0f);
    }
}

extern "C" void kernel_launch(void* const* d_in, const int* in_sizes, int n_in,
                              void* d_out, int out_size, void* d_ws, size_t ws_size,
                              hipStream_t stream) {
    const float* x    = (const float*)d_in[0];
    const float* emb  = (const float*)d_in[1];
    const float* W    = (const float*)d_in[2];
    const float* bias = (const float*)d_in[3];
    const int*   nbr  = (const int*)d_in[4];
    float* out = (float*)d_out;

    half2_t* xT = (half2_t*)d_ws;                              // 3.2 MB
    half8_t* gh = (half8_t*)((char*)d_ws + NN * 16 * sizeof(half2_t)); // 0.8 MB

    prep_kernel<<<(NN + TN - 1) / TN, 256, 0, stream>>>(x, emb, W, bias, xT, gh);
    gather_kernel<<<NN / GN, 256, 0, stream>>>((const half4_t*)xT, gh, W, nbr, out);
}